// Round 1
// baseline (1012.011 us; speedup 1.0000x reference)
//
#include <hip/hip_runtime.h>

#define DI __device__ __forceinline__

typedef unsigned int uint;
typedef unsigned short ushort;
typedef _Float16 half2t __attribute__((ext_vector_type(2)));

#define VOCAB 50257
#define NEMB 48
#define HID 128
#define G4 512
#define NCLS 2000
#define BATCH 512
#define SEQ 1024

#if __has_builtin(__builtin_amdgcn_fdot2)
DI float fdot2(half2t a, half2t b, float c) { return __builtin_amdgcn_fdot2(a, b, c, false); }
#else
DI float fdot2(half2t a, half2t b, float c) { return c + (float)a.x * (float)b.x + (float)a.y * (float)b.y; }
#endif

DI float sigm(float x) {
  return __builtin_amdgcn_rcpf(1.0f + __builtin_amdgcn_exp2f(-1.4426950408889634f * x));
}
DI float tanhfast(float x) {
  return 1.0f - 2.0f * __builtin_amdgcn_rcpf(__builtin_amdgcn_exp2f(2.8853900817779268f * x) + 1.0f);
}

// ---------------------------------------------------------------------------
// Phase A: P[v][j] = emb[v] . w_ih[j] + b_ih[j] + b_hh[j]  (fp32 math, f16 out)
// ---------------------------------------------------------------------------
#define VROWS 32
__global__ __launch_bounds__(512) void build_P(
    const float* __restrict__ emb, const float* __restrict__ w_ih,
    const float* __restrict__ b_ih, const float* __restrict__ b_hh,
    _Float16* __restrict__ P)
{
  __shared__ __align__(16) float eL[VROWS][NEMB];
  const int tid = threadIdx.x;
  const int v0 = blockIdx.x * VROWS;
  int nrows = VOCAB - v0; if (nrows > VROWS) nrows = VROWS;

  for (int f = tid; f < nrows * NEMB; f += 512)
    eL[f / NEMB][f % NEMB] = emb[(size_t)v0 * NEMB + f];

  float w[NEMB];
  {
    const float* wr = w_ih + (size_t)tid * NEMB;
#pragma unroll
    for (int k = 0; k < NEMB; k++) w[k] = wr[k];
  }
  float bias = b_ih[tid] + b_hh[tid];
  __syncthreads();

  for (int v = 0; v < nrows; v++) {
    const float4* e4 = (const float4*)&eL[v][0];
    float a = bias;
#pragma unroll
    for (int k = 0; k < NEMB / 4; k++) {
      float4 e = e4[k];
      a += w[4 * k] * e.x + w[4 * k + 1] * e.y + w[4 * k + 2] * e.z + w[4 * k + 3] * e.w;
    }
    P[(size_t)(v0 + v) * G4 + tid] = (_Float16)a;
  }
}

// ---------------------------------------------------------------------------
// Phase B: persistent LSTM scan. 512 blocks x 512 threads, ONE batch row per
// block, 2 blocks/CU -> 16 waves/CU. K-SPLIT layout: thread t owns gate cols
// (t&255) and (t&255)+256, but only K-half (t>>8) of the h.W_hh dot product.
// Per-thread weights = 64 VGPRs (was 128 -> no AGPR shuffling), h LDS read =
// 128B (its K-half). Partial sums combined as float2 in LDS; gate phase
// (tid<128) adds halves in fp32 and applies nonlinearities.
// ---------------------------------------------------------------------------
template<bool USE_P>
__global__ __launch_bounds__(512, 4) void lstm_scan(
    const int* __restrict__ x, const float* __restrict__ emb,
    const float* __restrict__ w_ih, const float* __restrict__ w_hh,
    const float* __restrict__ b_ih, const float* __restrict__ b_hh,
    const _Float16* __restrict__ P, float* __restrict__ hout)
{
  __shared__ int tokL[SEQ];
  __shared__ __align__(16) _Float16 h16[HID];
  __shared__ __align__(8) float2 g2[G4];          // .x = K-half0 partial, .y = K-half1
  __shared__ __align__(8) half2t e16[2][NEMB / 2];

  const int tid = threadIdx.x;        // 0..511
  const int b = blockIdx.x;
  const int col = tid & 255;          // owns gate cols col and col+256
  const int kh = tid >> 8;            // K-half 0/1 (wave-uniform)
  const int koff = kh * (HID / 2);    // element offset into h / W rows

  {
    const int* xp = x + (size_t)b * SEQ;
#pragma unroll
    for (int i = 0; i < SEQ / 512; i++) tokL[tid + 512 * i] = xp[tid + 512 * i];
  }

  // W_hh K-half rows for cols col and col+256, f16 pairs (2 x 32 = 64 VGPRs)
  half2t w0[HID / 4], w1[HID / 4];
  {
    const float4* wr0 = (const float4*)(w_hh + (size_t)col * HID + koff);
    const float4* wr1 = (const float4*)(w_hh + (size_t)(col + 256) * HID + koff);
#pragma unroll
    for (int k = 0; k < HID / 8; k++) {
      float4 a = wr0[k];
      half2t p; p.x = (_Float16)a.x; p.y = (_Float16)a.y; w0[2 * k] = p;
      p.x = (_Float16)a.z; p.y = (_Float16)a.w; w0[2 * k + 1] = p;
      float4 bv = wr1[k];
      p.x = (_Float16)bv.x; p.y = (_Float16)bv.y; w1[2 * k] = p;
      p.x = (_Float16)bv.z; p.y = (_Float16)bv.w; w1[2 * k + 1] = p;
    }
  }
  half2t wih0[NEMB / 2], wih1[NEMB / 2];
  float bias0 = 0.0f, bias1 = 0.0f;
  if (!USE_P && kh == 0) {
    const float* wr0 = w_ih + (size_t)col * NEMB;
    const float* wr1 = w_ih + (size_t)(col + 256) * NEMB;
#pragma unroll
    for (int k = 0; k < NEMB / 2; k++) {
      half2t p;
      p.x = (_Float16)wr0[2 * k]; p.y = (_Float16)wr0[2 * k + 1]; wih0[k] = p;
      p.x = (_Float16)wr1[2 * k]; p.y = (_Float16)wr1[2 * k + 1]; wih1[k] = p;
    }
    bias0 = b_ih[col] + b_hh[col];
    bias1 = b_ih[col + 256] + b_hh[col + 256];
  }
  if (tid < HID) h16[tid] = (_Float16)0.0f;
  __syncthreads(); // tokens + h16 visible

  float c = 0.0f;
  _Float16 pa0{}, pa1{}, pb0{}, pb1{};
  float2 einfl = {0.0f, 0.0f};
  if (USE_P) {
    if (kh == 0) {
      const _Float16* r0 = P + (size_t)tokL[0] * G4;
      const _Float16* r1 = P + (size_t)tokL[1] * G4;
      pa0 = r0[col]; pa1 = r0[col + 256];
      pb0 = r1[col]; pb1 = r1[col + 256];
    }
  } else {
    if (tid < NEMB / 2) {
      float2 e0 = ((const float2*)(emb + (size_t)tokL[0] * NEMB))[tid];
      einfl    = ((const float2*)(emb + (size_t)tokL[1] * NEMB))[tid];
      half2t p; p.x = (_Float16)e0.x; p.y = (_Float16)e0.y;
      e16[0][tid] = p;
    }
  }
  __syncthreads(); // e16[0] visible (no-op cost for USE_P)

#define STEP(t, par) do {                                                      \
    float xg0, xg1;                                                            \
    if (USE_P) {                                                               \
      if (kh == 0) {                                                           \
        int tc = (t) + 2; if (tc > SEQ - 1) tc = SEQ - 1;                      \
        xg0 = (float)((par) ? pb0 : pa0);                                      \
        xg1 = (float)((par) ? pb1 : pa1);                                      \
        const _Float16* rn = P + (size_t)tokL[tc] * G4; /* prefetch t+2 */     \
        _Float16 n0 = rn[col], n1 = rn[col + 256];                             \
        if ((par) == 0) { pa0 = n0; pa1 = n1; } else { pb0 = n0; pb1 = n1; }   \
      } else { xg0 = 0.0f; xg1 = 0.0f; }                                       \
    } else {                                                                   \
      if (tid < NEMB / 2) {                                                    \
        int tc = (t) + 2; if (tc > SEQ - 1) tc = SEQ - 1;                      \
        half2t p; p.x = (_Float16)einfl.x; p.y = (_Float16)einfl.y;            \
        e16[((t) + 1) & 1][tid] = p;                                           \
        einfl = ((const float2*)(emb + (size_t)tokL[tc] * NEMB))[tid];         \
      }                                                                        \
      if (kh == 0) {                                                           \
        xg0 = bias0; xg1 = bias1;                                              \
        _Pragma("unroll")                                                      \
        for (int k = 0; k < NEMB / 2; k++) {                                   \
          xg0 = fdot2(wih0[k], e16[(par)][k], xg0);                            \
          xg1 = fdot2(wih1[k], e16[(par)][k], xg1);                            \
        }                                                                      \
      } else { xg0 = 0.0f; xg1 = 0.0f; }                                       \
    }                                                                          \
    const uint4* hv = (const uint4*)h16 + (kh << 3);                           \
    float s0 = xg0, u0 = 0.0f, s1 = xg1, u1 = 0.0f;                            \
    _Pragma("unroll")                                                          \
    for (int kt = 0; kt < HID / 16; kt++) {                                    \
      uint4 hq = hv[kt];                                                       \
      half2t ha = __builtin_bit_cast(half2t, hq.x);                            \
      half2t hb = __builtin_bit_cast(half2t, hq.y);                            \
      half2t hc = __builtin_bit_cast(half2t, hq.z);                            \
      half2t hd = __builtin_bit_cast(half2t, hq.w);                            \
      s0 = fdot2(w0[4 * kt + 0], ha, s0);                                      \
      u0 = fdot2(w0[4 * kt + 1], hb, u0);                                      \
      s0 = fdot2(w0[4 * kt + 2], hc, s0);                                      \
      u0 = fdot2(w0[4 * kt + 3], hd, u0);                                      \
      s1 = fdot2(w1[4 * kt + 0], ha, s1);                                      \
      u1 = fdot2(w1[4 * kt + 1], hb, u1);                                      \
      s1 = fdot2(w1[4 * kt + 2], hc, s1);                                      \
      u1 = fdot2(w1[4 * kt + 3], hd, u1);                                      \
    }                                                                          \
    ((float*)&g2[col])[kh] = s0 + u0;                                          \
    ((float*)&g2[col + 256])[kh] = s1 + u1;                                    \
    __syncthreads();                                                           \
    if (tid < HID) {                                                           \
      float2 v0 = g2[tid],           v1 = g2[HID + tid];                       \
      float2 v2 = g2[2 * HID + tid], v3 = g2[3 * HID + tid];                   \
      float gi = v0.x + v0.y, gf = v1.x + v1.y;                                \
      float gc = v2.x + v2.y, go = v3.x + v3.y;                                \
      float fi = sigm(gi), ff = sigm(gf), gt = tanhfast(gc), fo = sigm(go);    \
      c = ff * c + fi * gt;                                                    \
      float hh = fo * tanhfast(c);                                             \
      h16[tid] = (_Float16)hh;                                                 \
      if ((t) == SEQ - 1) hout[(size_t)b * HID + tid] = hh;                    \
    }                                                                          \
    __syncthreads();                                                           \
  } while (0)

  for (int t = 0; t < SEQ; t += 2) { STEP(t, 0); STEP(t + 1, 1); }
#undef STEP
}

// ---------------------------------------------------------------------------
// Phase C: FC  out[512,2000] = h[512,128] @ w_fc^T + b_fc.  64x64 tiles,
// K=128 staged transposed in LDS, 4x4 register blocking per thread.
// ---------------------------------------------------------------------------
#define FCR 64
#define FCC 64
__global__ __launch_bounds__(256) void fc_kernel(
    const float* __restrict__ h, const float* __restrict__ w_fc,
    const float* __restrict__ b_fc, float* __restrict__ out)
{
  __shared__ float aT[HID][FCR];
  __shared__ float bT[HID][FCC];
  const int tid = threadIdx.x;
  const int r0 = blockIdx.y * FCR;
  const int c0 = blockIdx.x * FCC;

  for (int f = tid; f < FCR * (HID / 4); f += 256) {
    int row = f >> 5, q = f & 31;
    float4 v = ((const float4*)h)[(((size_t)(r0 + row)) << 5) + q];
    aT[4 * q + 0][row] = v.x; aT[4 * q + 1][row] = v.y;
    aT[4 * q + 2][row] = v.z; aT[4 * q + 3][row] = v.w;
    int wrow = c0 + row;
    float4 wv;
    if (wrow < NCLS) wv = ((const float4*)w_fc)[(((size_t)wrow) << 5) + q];
    else { wv.x = 0.f; wv.y = 0.f; wv.z = 0.f; wv.w = 0.f; }
    bT[4 * q + 0][row] = wv.x; bT[4 * q + 1][row] = wv.y;
    bT[4 * q + 2][row] = wv.z; bT[4 * q + 3][row] = wv.w;
  }
  __syncthreads();

  const int cr = tid & 15, rr = tid >> 4;
  float acc[4][4];
#pragma unroll
  for (int i = 0; i < 4; i++)
#pragma unroll
    for (int j = 0; j < 4; j++) acc[i][j] = 0.0f;

#pragma unroll 4
  for (int k = 0; k < HID; k++) {
    float4 av = *(const float4*)&aT[k][4 * rr];
    float4 bv = *(const float4*)&bT[k][4 * cr];
    float a[4] = {av.x, av.y, av.z, av.w};
    float bb[4] = {bv.x, bv.y, bv.z, bv.w};
#pragma unroll
    for (int i = 0; i < 4; i++)
#pragma unroll
      for (int j = 0; j < 4; j++) acc[i][j] += a[i] * bb[j];
  }

#pragma unroll
  for (int j = 0; j < 4; j++) {
    int cc = c0 + 4 * cr + j;
    if (cc < NCLS) {
      float bias = b_fc[cc];
#pragma unroll
      for (int i = 0; i < 4; i++)
        out[(size_t)(r0 + 4 * rr + i) * NCLS + cc] = acc[i][j] + bias;
    }
  }
}

extern "C" void kernel_launch(void* const* d_in, const int* in_sizes, int n_in,
                              void* d_out, int out_size, void* d_ws, size_t ws_size,
                              hipStream_t stream) {
  const int*   xx   = (const int*)d_in[0];
  const float* emb  = (const float*)d_in[1];
  const float* w_ih = (const float*)d_in[2];
  const float* w_hh = (const float*)d_in[3];
  const float* b_ih = (const float*)d_in[4];
  const float* b_hh = (const float*)d_in[5];
  const float* w_fc = (const float*)d_in[6];
  const float* b_fc = (const float*)d_in[7];
  float* out = (float*)d_out;

  const size_t pbytes = (size_t)VOCAB * G4 * sizeof(_Float16); // 51.5 MB
  const size_t palign = (pbytes + 255) & ~(size_t)255;
  const size_t hbytes = (size_t)BATCH * HID * sizeof(float);

  float* hout;
  if (ws_size >= palign + hbytes) {
    _Float16* P = (_Float16*)d_ws;
    hout = (float*)((char*)d_ws + palign);
    build_P<<<(VOCAB + VROWS - 1) / VROWS, 512, 0, stream>>>(emb, w_ih, b_ih, b_hh, P);
    lstm_scan<true><<<BATCH, 512, 0, stream>>>(xx, emb, w_ih, w_hh, b_ih, b_hh, P, hout);
  } else {
    hout = (float*)d_ws;
    lstm_scan<false><<<BATCH, 512, 0, stream>>>(xx, emb, w_ih, w_hh, b_ih, b_hh,
                                                (const _Float16*)nullptr, hout);
  }
  dim3 fcg((NCLS + FCC - 1) / FCC, BATCH / FCR);
  fc_kernel<<<fcg, 256, 0, stream>>>(hout, w_fc, b_fc, out);
}

// Round 2
// 1004.032 us; speedup vs baseline: 1.0079x; 1.0079x over previous
//
#include <hip/hip_runtime.h>

#define DI __device__ __forceinline__

typedef unsigned int uint;
typedef unsigned short ushort;
typedef _Float16 half2t __attribute__((ext_vector_type(2)));

#define VOCAB 50257
#define NEMB 48
#define HID 128
#define G4 512
#define NCLS 2000
#define BATCH 512
#define SEQ 1024

#if __has_builtin(__builtin_amdgcn_fdot2)
DI float fdot2(half2t a, half2t b, float c) { return __builtin_amdgcn_fdot2(a, b, c, false); }
#else
DI float fdot2(half2t a, half2t b, float c) { return c + (float)a.x * (float)b.x + (float)a.y * (float)b.y; }
#endif

DI float sigm(float x) {
  return __builtin_amdgcn_rcpf(1.0f + __builtin_amdgcn_exp2f(-1.4426950408889634f * x));
}
DI float tanhfast(float x) {
  return 1.0f - 2.0f * __builtin_amdgcn_rcpf(__builtin_amdgcn_exp2f(2.8853900817779268f * x) + 1.0f);
}

// Barrier that drains ONLY LDS (lgkmcnt), leaving global-load prefetches
// (vmcnt) in flight across the barrier. __syncthreads() would emit
// s_waitcnt vmcnt(0) and put the P-prefetch latency on the critical path
// of every timestep. Cross-thread data at these barriers is LDS-only.
DI void barrier_lds_only() {
  asm volatile("s_waitcnt lgkmcnt(0)" ::: "memory");
  __builtin_amdgcn_s_barrier();
  asm volatile("" ::: "memory");
}

// ---------------------------------------------------------------------------
// Phase A: P[v][j] = emb[v] . w_ih[j] + b_ih[j] + b_hh[j]  (fp32 math, f16 out)
// ---------------------------------------------------------------------------
#define VROWS 32
__global__ __launch_bounds__(512) void build_P(
    const float* __restrict__ emb, const float* __restrict__ w_ih,
    const float* __restrict__ b_ih, const float* __restrict__ b_hh,
    _Float16* __restrict__ P)
{
  __shared__ __align__(16) float eL[VROWS][NEMB];
  const int tid = threadIdx.x;
  const int v0 = blockIdx.x * VROWS;
  int nrows = VOCAB - v0; if (nrows > VROWS) nrows = VROWS;

  for (int f = tid; f < nrows * NEMB; f += 512)
    eL[f / NEMB][f % NEMB] = emb[(size_t)v0 * NEMB + f];

  float w[NEMB];
  {
    const float* wr = w_ih + (size_t)tid * NEMB;
#pragma unroll
    for (int k = 0; k < NEMB; k++) w[k] = wr[k];
  }
  float bias = b_ih[tid] + b_hh[tid];
  __syncthreads();

  for (int v = 0; v < nrows; v++) {
    const float4* e4 = (const float4*)&eL[v][0];
    float a = bias;
#pragma unroll
    for (int k = 0; k < NEMB / 4; k++) {
      float4 e = e4[k];
      a += w[4 * k] * e.x + w[4 * k + 1] * e.y + w[4 * k + 2] * e.z + w[4 * k + 3] * e.w;
    }
    P[(size_t)(v0 + v) * G4 + tid] = (_Float16)a;
  }
}

// ---------------------------------------------------------------------------
// Phase B: persistent LSTM scan. 512 blocks x 512 threads, ONE batch row per
// block, 2 blocks/CU. K-SPLIT: thread t owns gate cols (t&255, t&255+256),
// K-half (t>>8). Per-step barriers drain lgkmcnt ONLY so the 2-step-deep
// P prefetch stays in flight across barriers (vmcnt never force-drained).
// Partials in float g2h[2][512] (4B stride -> bank-conflict-free).
// ---------------------------------------------------------------------------
template<bool USE_P>
__global__ __launch_bounds__(512, 4) void lstm_scan(
    const int* __restrict__ x, const float* __restrict__ emb,
    const float* __restrict__ w_ih, const float* __restrict__ w_hh,
    const float* __restrict__ b_ih, const float* __restrict__ b_hh,
    const _Float16* __restrict__ P, float* __restrict__ hout)
{
  __shared__ int tokL[SEQ];
  __shared__ __align__(16) _Float16 h16[HID];
  __shared__ float g2h[2][G4];        // [kh][gate-col] partial sums
  __shared__ __align__(8) half2t e16[2][NEMB / 2];

  const int tid = threadIdx.x;        // 0..511
  const int b = blockIdx.x;
  const int col = tid & 255;          // owns gate cols col and col+256
  const int kh = tid >> 8;            // K-half 0/1 (wave-uniform)
  const int koff = kh * (HID / 2);    // element offset into h / W rows

  {
    const int* xp = x + (size_t)b * SEQ;
#pragma unroll
    for (int i = 0; i < SEQ / 512; i++) tokL[tid + 512 * i] = xp[tid + 512 * i];
  }

  // W_hh K-half rows for cols col and col+256, f16 pairs (2 x 32 = 64 VGPRs)
  half2t w0[HID / 4], w1[HID / 4];
  {
    const float4* wr0 = (const float4*)(w_hh + (size_t)col * HID + koff);
    const float4* wr1 = (const float4*)(w_hh + (size_t)(col + 256) * HID + koff);
#pragma unroll
    for (int k = 0; k < HID / 8; k++) {
      float4 a = wr0[k];
      half2t p; p.x = (_Float16)a.x; p.y = (_Float16)a.y; w0[2 * k] = p;
      p.x = (_Float16)a.z; p.y = (_Float16)a.w; w0[2 * k + 1] = p;
      float4 bv = wr1[k];
      p.x = (_Float16)bv.x; p.y = (_Float16)bv.y; w1[2 * k] = p;
      p.x = (_Float16)bv.z; p.y = (_Float16)bv.w; w1[2 * k + 1] = p;
    }
  }
  half2t wih0[NEMB / 2], wih1[NEMB / 2];
  float bias0 = 0.0f, bias1 = 0.0f;
  if (!USE_P && kh == 0) {
    const float* wr0 = w_ih + (size_t)col * NEMB;
    const float* wr1 = w_ih + (size_t)(col + 256) * NEMB;
#pragma unroll
    for (int k = 0; k < NEMB / 2; k++) {
      half2t p;
      p.x = (_Float16)wr0[2 * k]; p.y = (_Float16)wr0[2 * k + 1]; wih0[k] = p;
      p.x = (_Float16)wr1[2 * k]; p.y = (_Float16)wr1[2 * k + 1]; wih1[k] = p;
    }
    bias0 = b_ih[col] + b_hh[col];
    bias1 = b_ih[col + 256] + b_hh[col + 256];
  }
  if (tid < HID) h16[tid] = (_Float16)0.0f;
  __syncthreads(); // tokens + h16 visible (one-time full sync is fine)

  float c = 0.0f;
  _Float16 pa0{}, pa1{}, pb0{}, pb1{};
  float2 einfl = {0.0f, 0.0f};
  if (USE_P) {
    if (kh == 0) {
      const _Float16* r0 = P + (size_t)tokL[0] * G4;
      const _Float16* r1 = P + (size_t)tokL[1] * G4;
      pa0 = r0[col]; pa1 = r0[col + 256];
      pb0 = r1[col]; pb1 = r1[col + 256];
    }
  } else {
    if (tid < NEMB / 2) {
      float2 e0 = ((const float2*)(emb + (size_t)tokL[0] * NEMB))[tid];
      einfl    = ((const float2*)(emb + (size_t)tokL[1] * NEMB))[tid];
      half2t p; p.x = (_Float16)e0.x; p.y = (_Float16)e0.y;
      e16[0][tid] = p;
    }
  }
  __syncthreads();

#define STEP(t, par) do {                                                      \
    float xg0, xg1;                                                            \
    if (USE_P) {                                                               \
      if (kh == 0) {                                                           \
        int tc = (t) + 2; if (tc > SEQ - 1) tc = SEQ - 1;                      \
        xg0 = (float)((par) ? pb0 : pa0);                                      \
        xg1 = (float)((par) ? pb1 : pa1);                                      \
        const _Float16* rn = P + (size_t)tokL[tc] * G4; /* prefetch t+2 */     \
        _Float16 n0 = rn[col], n1 = rn[col + 256];                             \
        if ((par) == 0) { pa0 = n0; pa1 = n1; } else { pb0 = n0; pb1 = n1; }   \
      } else { xg0 = 0.0f; xg1 = 0.0f; }                                       \
    } else {                                                                   \
      if (tid < NEMB / 2) {                                                    \
        int tc = (t) + 2; if (tc > SEQ - 1) tc = SEQ - 1;                      \
        half2t p; p.x = (_Float16)einfl.x; p.y = (_Float16)einfl.y;            \
        e16[((t) + 1) & 1][tid] = p;                                           \
        einfl = ((const float2*)(emb + (size_t)tokL[tc] * NEMB))[tid];         \
      }                                                                        \
      if (kh == 0) {                                                           \
        xg0 = bias0; xg1 = bias1;                                              \
        _Pragma("unroll")                                                      \
        for (int k = 0; k < NEMB / 2; k++) {                                   \
          xg0 = fdot2(wih0[k], e16[(par)][k], xg0);                            \
          xg1 = fdot2(wih1[k], e16[(par)][k], xg1);                            \
        }                                                                      \
      } else { xg0 = 0.0f; xg1 = 0.0f; }                                       \
    }                                                                          \
    const uint4* hv = (const uint4*)h16 + (kh << 3);                           \
    float s0 = xg0, u0 = 0.0f, s1 = xg1, u1 = 0.0f;                            \
    _Pragma("unroll")                                                          \
    for (int kt = 0; kt < HID / 16; kt++) {                                    \
      uint4 hq = hv[kt];                                                       \
      half2t ha = __builtin_bit_cast(half2t, hq.x);                            \
      half2t hb = __builtin_bit_cast(half2t, hq.y);                            \
      half2t hc = __builtin_bit_cast(half2t, hq.z);                            \
      half2t hd = __builtin_bit_cast(half2t, hq.w);                            \
      s0 = fdot2(w0[4 * kt + 0], ha, s0);                                      \
      u0 = fdot2(w0[4 * kt + 1], hb, u0);                                      \
      s0 = fdot2(w0[4 * kt + 2], hc, s0);                                      \
      u0 = fdot2(w0[4 * kt + 3], hd, u0);                                      \
      s1 = fdot2(w1[4 * kt + 0], ha, s1);                                      \
      u1 = fdot2(w1[4 * kt + 1], hb, u1);                                      \
      s1 = fdot2(w1[4 * kt + 2], hc, s1);                                      \
      u1 = fdot2(w1[4 * kt + 3], hd, u1);                                      \
    }                                                                          \
    g2h[kh][col] = s0 + u0;                                                    \
    g2h[kh][col + 256] = s1 + u1;                                              \
    barrier_lds_only();                                                        \
    if (tid < HID) {                                                           \
      float gi = g2h[0][tid]           + g2h[1][tid];                          \
      float gf = g2h[0][HID + tid]     + g2h[1][HID + tid];                    \
      float gc = g2h[0][2 * HID + tid] + g2h[1][2 * HID + tid];                \
      float go = g2h[0][3 * HID + tid] + g2h[1][3 * HID + tid];                \
      float fi = sigm(gi), ff = sigm(gf), gt = tanhfast(gc), fo = sigm(go);    \
      c = ff * c + fi * gt;                                                    \
      float hh = fo * tanhfast(c);                                             \
      h16[tid] = (_Float16)hh;                                                 \
      if ((t) == SEQ - 1) hout[(size_t)b * HID + tid] = hh;                    \
    }                                                                          \
    barrier_lds_only();                                                        \
  } while (0)

  for (int t = 0; t < SEQ; t += 2) { STEP(t, 0); STEP(t + 1, 1); }
#undef STEP
}

// ---------------------------------------------------------------------------
// Phase C: FC  out[512,2000] = h[512,128] @ w_fc^T + b_fc.  64x64 tiles,
// K=128 staged transposed in LDS, 4x4 register blocking per thread.
// ---------------------------------------------------------------------------
#define FCR 64
#define FCC 64
__global__ __launch_bounds__(256) void fc_kernel(
    const float* __restrict__ h, const float* __restrict__ w_fc,
    const float* __restrict__ b_fc, float* __restrict__ out)
{
  __shared__ float aT[HID][FCR];
  __shared__ float bT[HID][FCC];
  const int tid = threadIdx.x;
  const int r0 = blockIdx.y * FCR;
  const int c0 = blockIdx.x * FCC;

  for (int f = tid; f < FCR * (HID / 4); f += 256) {
    int row = f >> 5, q = f & 31;
    float4 v = ((const float4*)h)[(((size_t)(r0 + row)) << 5) + q];
    aT[4 * q + 0][row] = v.x; aT[4 * q + 1][row] = v.y;
    aT[4 * q + 2][row] = v.z; aT[4 * q + 3][row] = v.w;
    int wrow = c0 + row;
    float4 wv;
    if (wrow < NCLS) wv = ((const float4*)w_fc)[(((size_t)wrow) << 5) + q];
    else { wv.x = 0.f; wv.y = 0.f; wv.z = 0.f; wv.w = 0.f; }
    bT[4 * q + 0][row] = wv.x; bT[4 * q + 1][row] = wv.y;
    bT[4 * q + 2][row] = wv.z; bT[4 * q + 3][row] = wv.w;
  }
  __syncthreads();

  const int cr = tid & 15, rr = tid >> 4;
  float acc[4][4];
#pragma unroll
  for (int i = 0; i < 4; i++)
#pragma unroll
    for (int j = 0; j < 4; j++) acc[i][j] = 0.0f;

#pragma unroll 4
  for (int k = 0; k < HID; k++) {
    float4 av = *(const float4*)&aT[k][4 * rr];
    float4 bv = *(const float4*)&bT[k][4 * cr];
    float a[4] = {av.x, av.y, av.z, av.w};
    float bb[4] = {bv.x, bv.y, bv.z, bv.w};
#pragma unroll
    for (int i = 0; i < 4; i++)
#pragma unroll
      for (int j = 0; j < 4; j++) acc[i][j] += a[i] * bb[j];
  }

#pragma unroll
  for (int j = 0; j < 4; j++) {
    int cc = c0 + 4 * cr + j;
    if (cc < NCLS) {
      float bias = b_fc[cc];
#pragma unroll
      for (int i = 0; i < 4; i++)
        out[(size_t)(r0 + 4 * rr + i) * NCLS + cc] = acc[i][j] + bias;
    }
  }
}

extern "C" void kernel_launch(void* const* d_in, const int* in_sizes, int n_in,
                              void* d_out, int out_size, void* d_ws, size_t ws_size,
                              hipStream_t stream) {
  const int*   xx   = (const int*)d_in[0];
  const float* emb  = (const float*)d_in[1];
  const float* w_ih = (const float*)d_in[2];
  const float* w_hh = (const float*)d_in[3];
  const float* b_ih = (const float*)d_in[4];
  const float* b_hh = (const float*)d_in[5];
  const float* w_fc = (const float*)d_in[6];
  const float* b_fc = (const float*)d_in[7];
  float* out = (float*)d_out;

  const size_t pbytes = (size_t)VOCAB * G4 * sizeof(_Float16); // 51.5 MB
  const size_t palign = (pbytes + 255) & ~(size_t)255;
  const size_t hbytes = (size_t)BATCH * HID * sizeof(float);

  float* hout;
  if (ws_size >= palign + hbytes) {
    _Float16* P = (_Float16*)d_ws;
    hout = (float*)((char*)d_ws + palign);
    build_P<<<(VOCAB + VROWS - 1) / VROWS, 512, 0, stream>>>(emb, w_ih, b_ih, b_hh, P);
    lstm_scan<true><<<BATCH, 512, 0, stream>>>(xx, emb, w_ih, w_hh, b_ih, b_hh, P, hout);
  } else {
    hout = (float*)d_ws;
    lstm_scan<false><<<BATCH, 512, 0, stream>>>(xx, emb, w_ih, w_hh, b_ih, b_hh,
                                                (const _Float16*)nullptr, hout);
  }
  dim3 fcg((NCLS + FCC - 1) / FCC, BATCH / FCR);
  fc_kernel<<<fcg, 256, 0, stream>>>(hout, w_fc, b_fc, out);
}